// Round 3
// baseline (247.730 us; speedup 1.0000x reference)
//
#include <hip/hip_runtime.h>

// LocalCorrelation on MI355X (gfx950).  R3.
// nt: float4 loads (16 indep), sumsq from registers, f16 LDS tile [c][64w] with
//     XOR swizzle (w ^ 8*(c>>5)) -> <=2-way banks both phases; paired-pixel b32
//     transposed reads; f32 scaling (precision = R2).
// corr: 8-wave blocks, 4 h-rows x 16 w, 16x16x32 f16 band-GEMM; 4 staging
//     jobs/thread; b cols padded to 32 (conflict-free b128 frag reads).

typedef _Float16 half8 __attribute__((ext_vector_type(8)));
typedef _Float16 half2v __attribute__((ext_vector_type(2)));
typedef float floatx4 __attribute__((ext_vector_type(4)));

#define B_ 4
#define C_ 256
#define H_ 128
#define W_ 128
#define K2_ 169
#define INV_T 14.285714285714286f

// ---------------- Pass 1: normalize + transpose ----------------
// Block: (tensor, b, h, wh) -> 64 w-pixels, 256 threads, 2048 blocks.
__global__ __launch_bounds__(256) void nt_kernel(const float* __restrict__ fa,
                                                 const float* __restrict__ fb,
                                                 _Float16* __restrict__ an,
                                                 _Float16* __restrict__ bn) {
  __shared__ _Float16 tile[256 * 66];  // 33792 B, row stride 66 hw (33 dw, odd)
  __shared__ float ps[16 * 64];        // 4 KB
  __shared__ float invn[64];
  const int bid = blockIdx.x;
  const int wh = bid & 1, h = (bid >> 1) & 127, bb = (bid >> 8) & 3, tens = bid >> 10;
  const float* __restrict__ src = tens ? fb : fa;
  _Float16* __restrict__ dst = tens ? bn : an;
  const int t = threadIdx.x;
  const int f = t & 15, cp = t >> 4;  // w = wh*64 + f*4 ; c = it*16 + cp

  const float* gs = src + (((size_t)bb * C_ + cp) * H_ + h) * W_ + wh * 64 + f * 4;
  floatx4 ss = {0.f, 0.f, 0.f, 0.f};
  #pragma unroll
  for (int it = 0; it < 16; ++it) {
    const floatx4 v = *(const floatx4*)(gs + (size_t)it * 16 * H_ * W_);
    ss += v * v;
    const int c = it * 16 + cp;
    const int s8 = ((c >> 5) & 7) * 8;           // XOR swizzle, wave-uniform per it
    _Float16* wp = tile + c * 66 + ((f * 4) ^ s8);
    half2v p0 = {(_Float16)v.x, (_Float16)v.y};
    half2v p1 = {(_Float16)v.z, (_Float16)v.w};
    *(half2v*)wp = p0;
    *(half2v*)(wp + 2) = p1;                     // 4B-aligned b32 pair (odd rows are 4B-aligned)
  }
  *(floatx4*)(ps + cp * 64 + f * 4) = ss;
  __syncthreads();
  if (t < 64) {
    float s2 = 0.f;
    #pragma unroll
    for (int p = 0; p < 16; ++p) s2 += ps[p * 64 + t];
    invn[t] = 1.0f / fmaxf(sqrtf(s2), 1e-12f);
  }
  __syncthreads();

  // Phase 2: thread = (pixel pair 2pr,2pr+1; c-chunk seg*32..+31). 32 b32 reads,
  // bank = j + (pr ^ 4*seg) -> exact 2-to-1 (free).
  const int pr = t >> 3, seg = t & 7;
  const float inv0 = invn[2 * pr], inv1 = invn[2 * pr + 1];
  const int ppr = pr ^ (4 * seg);
  _Float16 o0[32] __attribute__((aligned(16)));
  _Float16 o1[32] __attribute__((aligned(16)));
  #pragma unroll
  for (int j = 0; j < 32; ++j) {
    const int c = seg * 32 + j;                  // c>>5 == seg -> swizzle consistent
    const half2v d = *(const half2v*)(tile + c * 66 + ppr * 2);
    o0[j] = (_Float16)((float)d.x * inv0);
    o1[j] = (_Float16)((float)d.y * inv1);
  }
  _Float16* dp = dst + (((size_t)bb * H_ + h) * W_ + wh * 64 + 2 * pr) * C_ + seg * 32;
  #pragma unroll
  for (int q4 = 0; q4 < 4; ++q4) {
    *(uint4*)(dp + q4 * 8) = *(const uint4*)(o0 + q4 * 8);
    *(uint4*)(dp + C_ + q4 * 8) = *(const uint4*)(o1 + q4 * 8);
  }
}

// ---------------- Pass 2: band-GEMM correlation ----------------
// LDS (halfword offsets):
//   a: [0, 2560)   a[px*40 + sg*8], px = r*16 + m   (stride 40 hw = 80 B)
//   b: [2560, +16384)  b[sg*4096 + (row*32 + col)*8], 16 rows x 32 cols (28 used)
struct StageS { _Float16 a[2560]; _Float16 b[16384]; };  // 37888 B
union SmemU { StageS s; float ostage[K2_ * 4 * 17]; };   // 45968 B

__global__ __launch_bounds__(512, 4) void corr_kernel(const _Float16* __restrict__ an,
                                                      const _Float16* __restrict__ bn,
                                                      float* __restrict__ out) {
  __shared__ SmemU u;
  const int bid = blockIdx.x;
  const int xcd = bid & 7, l = bid >> 3;       // XCD-contiguous h-bands
  const int bb = l >> 5, hseg = (l >> 3) & 3, wt = l & 7;
  const int hg = xcd * 4 + hseg;
  const int h0 = hg * 4, w0 = wt * 16;
  const int t = threadIdx.x;
  const int lane = t & 63, wv = t >> 6;        // 8 waves
  const int ml = lane & 15, q = lane >> 4;
  const int ntile = wv & 1, jjg = wv >> 1;     // halo-col tile, jj mod 4

  _Float16* const smem = (_Float16*)&u.s;

  // job table: 4 jobs/thread. 0..1791 b-halo (16 rows x 28 cols x 4 sg, sg-major),
  // 1792..2047 a-tile (64 px x 4 sg).
  const _Float16* gptr[4];
  int loff[4];
  unsigned flags = 0u;
  #pragma unroll
  for (int j = 0; j < 4; ++j) {
    const int job = j * 512 + t;
    if (job < 1792) {
      const int sg = job / 448, px = job - sg * 448;
      const int row = px / 28, col = px - row * 28;
      const int rim = h0 - 6 + row, cim = w0 - 6 + col;
      const bool ok = ((unsigned)rim < (unsigned)H_) && ((unsigned)cim < (unsigned)W_);
      gptr[j] = bn + (((size_t)bb * H_ + (ok ? rim : 0)) * W_ + (ok ? cim : 0)) * C_ + sg * 8;
      loff[j] = 2560 + sg * 4096 + (row * 32 + col) * 8;
      if (ok) flags |= 1u << j;
    } else {
      const int jb = job - 1792;
      const int px = jb >> 2, sg = jb & 3;
      const int r = px >> 4, m = px & 15;
      gptr[j] = an + (((size_t)bb * H_ + h0 + r) * W_ + w0 + m) * C_ + sg * 8;
      loff[j] = px * 40 + sg * 8;
      flags |= 1u << j;
    }
  }

  floatx4 acc[4][4] = {};  // [uu: jj=jjg+4uu][r]; 13 of 16 valid per wave

  #pragma unroll
  for (int k0 = 0; k0 < C_; k0 += 32) {
    __syncthreads();
    #pragma unroll
    for (int j = 0; j < 4; ++j) {
      uint4 v = make_uint4(0u, 0u, 0u, 0u);
      if (flags & (1u << j)) v = *(const uint4*)(gptr[j] + k0);
      *(uint4*)(smem + loff[j]) = v;
    }
    __syncthreads();

    half8 A[4];
    #pragma unroll
    for (int r = 0; r < 4; ++r)
      A[r] = *(const half8*)(smem + (r * 16 + ml) * 40 + q * 8);

    #pragma unroll
    for (int uu = 0; uu < 4; ++uu) {
      const int jj = jjg + 4 * uu;
      const half8 Bf =
          *(const half8*)(smem + 2560 + q * 4096 + (jj * 32 + ntile * 16 + ml) * 8);
      #pragma unroll
      for (int r = 0; r < 4; ++r) {
        // valid iff 0 <= jj - r <= 12; only uu==0 (r<=jjg) and uu==3 (r>=jjg) constrain
        if ((uu == 0 && r > jjg) || (uu == 3 && r < jjg)) continue;
        acc[uu][r] = __builtin_amdgcn_mfma_f32_16x16x32_f16(A[r], Bf, acc[uu][r], 0, 0, 0);
      }
    }
  }
  __syncthreads();  // staging reads done before ostage overwrite

  // epilogue: C/D layout col=lane&15, row=(lane>>4)*4+p
  #pragma unroll
  for (int uu = 0; uu < 4; ++uu) {
    const int jj = jjg + 4 * uu;
    const int col = ntile * 16 + ml;
    #pragma unroll
    for (int r = 0; r < 4; ++r) {
      if ((uu == 0 && r > jjg) || (uu == 3 && r < jjg)) continue;
      const int dy6 = jj - r;  // in [0,12] for all kept pairs
      #pragma unroll
      for (int p = 0; p < 4; ++p) {
        const int ip = q * 4 + p;
        const int dx6 = col - ip;
        if (dx6 >= 0 && dx6 <= 12)
          u.ostage[((dy6 * 13 + dx6) * 4 + r) * 17 + ip] = acc[uu][r][p] * INV_T;
      }
    }
  }
  __syncthreads();

  for (int sidx = t; sidx < K2_ * 64; sidx += 512) {
    const int k = sidx >> 6, rem = sidx & 63, r = rem >> 4, ip = rem & 15;
    out[(((size_t)bb * K2_ + k) * H_ + h0 + r) * W_ + w0 + ip] =
        u.ostage[(k * 4 + r) * 17 + ip];
  }
}

extern "C" void kernel_launch(void* const* d_in, const int* in_sizes, int n_in,
                              void* d_out, int out_size, void* d_ws, size_t ws_size,
                              hipStream_t stream) {
  const float* fa = (const float*)d_in[0];
  const float* fb = (const float*)d_in[1];
  float* out = (float*)d_out;
  _Float16* an = (_Float16*)d_ws;                 // 33.55 MB
  _Float16* bn = an + (size_t)B_ * H_ * W_ * C_;  // 33.55 MB
  nt_kernel<<<2048, 256, 0, stream>>>(fa, fb, an, bn);
  corr_kernel<<<1024, 512, 0, stream>>>(an, bn, out);
}

// Round 5
// 205.146 us; speedup vs baseline: 1.2076x; 1.2076x over previous
//
#include <hip/hip_runtime.h>
#include <stdint.h>

// LocalCorrelation on MI355X (gfx950).  R5 = R4 + exec-mask-safe DMA base.
// Workspace layout k-chunk-major: [b][kg(8)][h][w][32ch].
// corr staging via global_load_lds(16B): LDS dest is wave-uniform base + lane*16
// (m104/m108). R4 passed per-lane lds ptrs under partial exec -> readfirstlane
// picked a shifted base on edge blocks (the absmax=6.4 bug). R5 passes the
// SAME uniform base from every lane: (j*512 + wv*64)*16 (valid since the
// a-region offset 28672 == 1792*16 makes lb = job*16 globally linear).
// OOB lanes stay exec-masked; their slots keep prologue zeros.

typedef _Float16 half8 __attribute__((ext_vector_type(8)));
typedef _Float16 half2v __attribute__((ext_vector_type(2)));
typedef float floatx4 __attribute__((ext_vector_type(4)));

#define B_ 4
#define C_ 256
#define H_ 128
#define W_ 128
#define K2_ 169
#define INV_T 14.285714285714286f
#define KGS (H_ * W_ * 32)  // element stride between kg planes (per b)

static __device__ __forceinline__ void gload16(const void* g, void* l) {
  __builtin_amdgcn_global_load_lds((const __attribute__((address_space(1))) void*)g,
                                   (__attribute__((address_space(3))) void*)l, 16, 0, 0);
}

// ---------------- Pass 1: normalize + transpose ----------------
__global__ __launch_bounds__(256) void nt_kernel(const float* __restrict__ fa,
                                                 const float* __restrict__ fb,
                                                 _Float16* __restrict__ an,
                                                 _Float16* __restrict__ bn) {
  __shared__ _Float16 tile[256 * 66];  // XOR-swizzled [c][64w]
  __shared__ float ps[16 * 64];
  __shared__ float invn[64];
  const int bid = blockIdx.x;
  const int wh = bid & 1, h = (bid >> 1) & 127, bb = (bid >> 8) & 3, tens = bid >> 10;
  const float* __restrict__ src = tens ? fb : fa;
  _Float16* __restrict__ dst = tens ? bn : an;
  const int t = threadIdx.x;
  const int f = t & 15, cp = t >> 4;  // w = wh*64 + f*4 ; c = it*16 + cp

  const float* gs = src + (((size_t)bb * C_ + cp) * H_ + h) * W_ + wh * 64 + f * 4;
  floatx4 ss = {0.f, 0.f, 0.f, 0.f};
  #pragma unroll
  for (int it = 0; it < 16; ++it) {
    const floatx4 v = *(const floatx4*)(gs + (size_t)it * 16 * H_ * W_);
    ss += v * v;
    const int c = it * 16 + cp;
    const int s8 = ((c >> 5) & 7) * 8;  // XOR swizzle (element w -> column w^s8)
    _Float16* wp = tile + c * 66 + ((f * 4) ^ s8);
    half2v p0 = {(_Float16)v.x, (_Float16)v.y};
    half2v p1 = {(_Float16)v.z, (_Float16)v.w};
    *(half2v*)wp = p0;
    *(half2v*)(wp + 2) = p1;
  }
  *(floatx4*)(ps + cp * 64 + f * 4) = ss;
  __syncthreads();
  if (t < 64) {
    float s2 = 0.f;
    #pragma unroll
    for (int p = 0; p < 16; ++p) s2 += ps[p * 64 + t];
    invn[t] = 1.0f / fmaxf(sqrtf(s2), 1e-12f);
  }
  __syncthreads();

  // Phase 2: thread = (kg plane seg = t>>5, pixel pair pr = t&31).
  const int seg = t >> 5, pr = t & 31;
  const float sc = tens ? 1.0f : INV_T;  // fold 1/T into a
  const float inv0 = invn[2 * pr] * sc, inv1 = invn[2 * pr + 1] * sc;
  const int ppr = pr ^ (4 * seg);
  _Float16 o0[32] __attribute__((aligned(16)));
  _Float16 o1[32] __attribute__((aligned(16)));
  #pragma unroll
  for (int j = 0; j < 32; ++j) {
    const int c = seg * 32 + j;  // c>>5 == seg -> swizzle consistent
    const half2v d = *(const half2v*)(tile + c * 66 + ppr * 2);
    o0[j] = (_Float16)((float)d.x * inv0);
    o1[j] = (_Float16)((float)d.y * inv1);
  }
  _Float16* dp = dst + ((((size_t)bb * 8 + seg) * H_ + h) * W_ + wh * 64 + 2 * pr) * 32;
  #pragma unroll
  for (int q4 = 0; q4 < 4; ++q4) {
    *(uint4*)(dp + q4 * 8) = *(const uint4*)(o0 + q4 * 8);
    *(uint4*)(dp + 32 + q4 * 8) = *(const uint4*)(o1 + q4 * 8);
  }
}

// ---------------- Pass 2: band-GEMM correlation ----------------
// Per 32 KB buffer, LDS byte offset of job = job*16:
//   b-halo jobs [0, 28672): job = (row*28+col)*4+qt ; a jobs [28672, 32768).
// Frag reads (hw): A[r] at 14336 + (r*16+ml)*32 + q*8 ; B at jj*896 + col*32 + q*8.
union SmemU { _Float16 stage[2][16384]; float ostage[K2_ * 2 * 17]; };  // 64 KB

__global__ __launch_bounds__(512, 4) void corr_kernel(const _Float16* __restrict__ an,
                                                      const _Float16* __restrict__ bn,
                                                      float* __restrict__ out) {
  __shared__ SmemU u;
  const int bid = blockIdx.x;
  const int xcd = bid & 7, l = bid >> 3;  // XCD-contiguous h-bands
  const int bb = l >> 5, hseg = (l >> 3) & 3, wt = l & 7;
  const int hg = xcd * 4 + hseg;
  const int h0 = hg * 4, w0 = wt * 16;
  const int t = threadIdx.x;
  const int lane = t & 63, wv = t >> 6;  // 8 waves
  const int ml = lane & 15, q = lane >> 4;
  const int ntile = wv & 1, jjg = wv >> 1;

  // ---- job table (once): global ptrs + validity; LDS offset of job j is
  //      (j*512 + t)*16 bytes, wave-uniform base (j*512 + wv*64)*16. ----
  const _Float16* ptr[4];
  unsigned flags = 0u;
  #pragma unroll
  for (int j = 0; j < 4; ++j) {
    const int job = j * 512 + t;
    if (job < 1792) {  // b-halo: 16 rows x 28 cols x 4 quarters
      const int row = job / 112, rem = job - row * 112;
      const int col = rem >> 2, qt = rem & 3;
      const int rim = h0 - 6 + row, cim = w0 - 6 + col;
      const bool ok = ((unsigned)rim < (unsigned)H_) && ((unsigned)cim < (unsigned)W_);
      ptr[j] = bn + (((size_t)bb * 8 * H_ + (ok ? rim : 0)) * W_ + (ok ? cim : 0)) * 32 + qt * 8;
      if (ok) flags |= 1u << j;
    } else {           // a-tile: 64 px (r*16+m) x 4 quarters
      const int aj = job - 1792;
      const int px = aj >> 2, qt = aj & 3;
      const int r = px >> 4, m = px & 15;
      ptr[j] = an + (((size_t)bb * 8 * H_ + h0 + r) * W_ + w0 + m) * 32 + qt * 8;
      flags |= 1u << j;
    }
  }

  // ---- prologue: zero all slots of both buffers (OOB slots stay zero) ----
  const uint4 z4 = make_uint4(0u, 0u, 0u, 0u);
  #pragma unroll
  for (int j = 0; j < 4; ++j) {
    *(uint4*)((char*)u.stage[0] + (j * 512 + t) * 16) = z4;
    *(uint4*)((char*)u.stage[1] + (j * 512 + t) * 16) = z4;
  }
  __syncthreads();

  // stage kg=0 into buf0 (uniform LDS base per wave+j, safe under exec mask)
  #pragma unroll
  for (int j = 0; j < 4; ++j) {
    if (flags & (1u << j))
      gload16(ptr[j], (char*)u.stage[0] + (j * 512 + wv * 64) * 16);
    ptr[j] += KGS;
  }

  floatx4 acc[4][4] = {};  // [uu: jj=jjg+4uu][r]; 13 of 16 valid per wave

  for (int kg = 0; kg < 8; ++kg) {
    __syncthreads();  // drains kg's DMA; all kg-1 frag reads already complete
    if (kg < 7) {
      char* nb = (char*)u.stage[(kg + 1) & 1];
      #pragma unroll
      for (int j = 0; j < 4; ++j) {
        if (flags & (1u << j))
          gload16(ptr[j], nb + (j * 512 + wv * 64) * 16);
        ptr[j] += KGS;
      }
    }
    const _Float16* sb = u.stage[kg & 1];

    half8 A[4];
    #pragma unroll
    for (int r = 0; r < 4; ++r)
      A[r] = *(const half8*)(sb + 14336 + (r * 16 + ml) * 32 + q * 8);

    #pragma unroll
    for (int uu = 0; uu < 4; ++uu) {
      const int jj = jjg + 4 * uu;
      const half8 Bf = *(const half8*)(sb + jj * 896 + (ntile * 16 + ml) * 32 + q * 8);
      #pragma unroll
      for (int r = 0; r < 4; ++r) {
        if ((uu == 0 && r > jjg) || (uu == 3 && r < jjg)) continue;  // dy out of band
        acc[uu][r] = __builtin_amdgcn_mfma_f32_16x16x32_f16(A[r], Bf, acc[uu][r], 0, 0, 0);
      }
    }
  }

  // ---- epilogue: 2 rounds of 2 rows; ostage (22984 B) overlays buf0 only ----
  // C/D layout: col = lane&15 (halo col j), row = q*4+p (w-pixel i); dx6 = j - i.
  #pragma unroll
  for (int r2 = 0; r2 < 2; ++r2) {
    if (r2) __syncthreads();  // round-0 store reads done before rewrite
    #pragma unroll
    for (int uu = 0; uu < 4; ++uu) {
      const int jj = jjg + 4 * uu;
      const int col = ntile * 16 + ml;
      #pragma unroll
      for (int rr = 2 * r2; rr < 2 * r2 + 2; ++rr) {
        if ((uu == 0 && rr > jjg) || (uu == 3 && rr < jjg)) continue;
        const int dy6 = jj - rr;  // in [0,12]
        #pragma unroll
        for (int p = 0; p < 4; ++p) {
          const int ip = q * 4 + p;
          const int dx6 = col - ip;
          if (dx6 >= 0 && dx6 <= 12)
            u.ostage[((dy6 * 13 + dx6) * 2 + (rr & 1)) * 17 + ip] = acc[uu][rr][p];
        }
      }
    }
    __syncthreads();
    for (int s = t; s < K2_ * 32; s += 512) {
      const int k = s >> 5, r1 = (s >> 4) & 1, ip = s & 15;
      out[(((size_t)bb * K2_ + k) * H_ + h0 + 2 * r2 + r1) * W_ + w0 + ip] =
          u.ostage[(k * 2 + r1) * 17 + ip];
    }
  }
}

extern "C" void kernel_launch(void* const* d_in, const int* in_sizes, int n_in,
                              void* d_out, int out_size, void* d_ws, size_t ws_size,
                              hipStream_t stream) {
  const float* fa = (const float*)d_in[0];
  const float* fb = (const float*)d_in[1];
  float* out = (float*)d_out;
  _Float16* an = (_Float16*)d_ws;                 // 33.55 MB, [b][kg][h][w][32]
  _Float16* bn = an + (size_t)B_ * H_ * W_ * C_;  // 33.55 MB
  nt_kernel<<<2048, 256, 0, stream>>>(fa, fb, an, bn);
  corr_kernel<<<1024, 512, 0, stream>>>(an, bn, out);
}

// Round 6
// 202.689 us; speedup vs baseline: 1.2222x; 1.0121x over previous
//
#include <hip/hip_runtime.h>
#include <stdint.h>

// LocalCorrelation on MI355X (gfx950).  R6 = R5 + register-blocked nt loads.
// R5 post-mortem: nt was latency-bound (VGPR=52 -> only ~4 of 16 loads in
// flight; VALUBusy 5%, HBM 22%). R6 loads all 16 float4 into a register array
// (forces ~64 live VGPRs -> 16 loads issued back-to-back), then processes in
// arrival order. __launch_bounds__(256,4): cap 128 VGPR, matches the 4
// blocks/CU LDS limit. corr kernel unchanged from R5 (passed, conflict-free).

typedef _Float16 half8 __attribute__((ext_vector_type(8)));
typedef _Float16 half2v __attribute__((ext_vector_type(2)));
typedef float floatx4 __attribute__((ext_vector_type(4)));

#define B_ 4
#define C_ 256
#define H_ 128
#define W_ 128
#define K2_ 169
#define INV_T 14.285714285714286f
#define KGS (H_ * W_ * 32)  // element stride between kg planes (per b)

static __device__ __forceinline__ void gload16(const void* g, void* l) {
  __builtin_amdgcn_global_load_lds((const __attribute__((address_space(1))) void*)g,
                                   (__attribute__((address_space(3))) void*)l, 16, 0, 0);
}

// ---------------- Pass 1: normalize + transpose ----------------
__global__ __launch_bounds__(256, 4) void nt_kernel(const float* __restrict__ fa,
                                                    const float* __restrict__ fb,
                                                    _Float16* __restrict__ an,
                                                    _Float16* __restrict__ bn) {
  __shared__ _Float16 tile[256 * 66];  // XOR-swizzled [c][64w]
  __shared__ float ps[16 * 64];
  __shared__ float invn[64];
  const int bid = blockIdx.x;
  const int wh = bid & 1, h = (bid >> 1) & 127, bb = (bid >> 8) & 3, tens = bid >> 10;
  const float* __restrict__ src = tens ? fb : fa;
  _Float16* __restrict__ dst = tens ? bn : an;
  const int t = threadIdx.x;
  const int f = t & 15, cp = t >> 4;  // w = wh*64 + f*4 ; c = it*16 + cp

  const float* gs = src + (((size_t)bb * C_ + cp) * H_ + h) * W_ + wh * 64 + f * 4;

  // issue ALL 16 loads before any use (64 live VGPRs -> full MLP)
  floatx4 v[16];
  #pragma unroll
  for (int it = 0; it < 16; ++it)
    v[it] = *(const floatx4*)(gs + (size_t)it * 16 * H_ * W_);

  floatx4 ss0 = {0.f, 0.f, 0.f, 0.f}, ss1 = {0.f, 0.f, 0.f, 0.f};
  #pragma unroll
  for (int it = 0; it < 16; ++it) {
    if (it & 1) ss1 += v[it] * v[it]; else ss0 += v[it] * v[it];
    const int c = it * 16 + cp;
    const int s8 = ((c >> 5) & 7) * 8;  // XOR swizzle (element w -> column w^s8)
    _Float16* wp = tile + c * 66 + ((f * 4) ^ s8);
    half2v p0 = {(_Float16)v[it].x, (_Float16)v[it].y};
    half2v p1 = {(_Float16)v[it].z, (_Float16)v[it].w};
    *(half2v*)wp = p0;
    *(half2v*)(wp + 2) = p1;
  }
  const floatx4 ss = ss0 + ss1;
  *(floatx4*)(ps + cp * 64 + f * 4) = ss;
  __syncthreads();
  if (t < 64) {
    float s2 = 0.f;
    #pragma unroll
    for (int p = 0; p < 16; ++p) s2 += ps[p * 64 + t];
    invn[t] = 1.0f / fmaxf(sqrtf(s2), 1e-12f);
  }
  __syncthreads();

  // Phase 2: thread = (kg plane seg = t>>5, pixel pair pr = t&31).
  const int seg = t >> 5, pr = t & 31;
  const float sc = tens ? 1.0f : INV_T;  // fold 1/T into a
  const float inv0 = invn[2 * pr] * sc, inv1 = invn[2 * pr + 1] * sc;
  const int ppr = pr ^ (4 * seg);
  _Float16 o0[32] __attribute__((aligned(16)));
  _Float16 o1[32] __attribute__((aligned(16)));
  #pragma unroll
  for (int j = 0; j < 32; ++j) {
    const int c = seg * 32 + j;  // c>>5 == seg -> swizzle consistent
    const half2v d = *(const half2v*)(tile + c * 66 + ppr * 2);
    o0[j] = (_Float16)((float)d.x * inv0);
    o1[j] = (_Float16)((float)d.y * inv1);
  }
  _Float16* dp = dst + ((((size_t)bb * 8 + seg) * H_ + h) * W_ + wh * 64 + 2 * pr) * 32;
  #pragma unroll
  for (int q4 = 0; q4 < 4; ++q4) {
    *(uint4*)(dp + q4 * 8) = *(const uint4*)(o0 + q4 * 8);
    *(uint4*)(dp + 32 + q4 * 8) = *(const uint4*)(o1 + q4 * 8);
  }
}

// ---------------- Pass 2: band-GEMM correlation (unchanged from R5) ----------------
// Per 32 KB buffer, LDS byte offset of job = job*16:
//   b-halo jobs [0, 28672): job = (row*28+col)*4+qt ; a jobs [28672, 32768).
// Frag reads (hw): A[r] at 14336 + (r*16+ml)*32 + q*8 ; B at jj*896 + col*32 + q*8.
union SmemU { _Float16 stage[2][16384]; float ostage[K2_ * 2 * 17]; };  // 64 KB

__global__ __launch_bounds__(512, 4) void corr_kernel(const _Float16* __restrict__ an,
                                                      const _Float16* __restrict__ bn,
                                                      float* __restrict__ out) {
  __shared__ SmemU u;
  const int bid = blockIdx.x;
  const int xcd = bid & 7, l = bid >> 3;  // XCD-contiguous h-bands
  const int bb = l >> 5, hseg = (l >> 3) & 3, wt = l & 7;
  const int hg = xcd * 4 + hseg;
  const int h0 = hg * 4, w0 = wt * 16;
  const int t = threadIdx.x;
  const int lane = t & 63, wv = t >> 6;  // 8 waves
  const int ml = lane & 15, q = lane >> 4;
  const int ntile = wv & 1, jjg = wv >> 1;

  const _Float16* ptr[4];
  unsigned flags = 0u;
  #pragma unroll
  for (int j = 0; j < 4; ++j) {
    const int job = j * 512 + t;
    if (job < 1792) {  // b-halo: 16 rows x 28 cols x 4 quarters
      const int row = job / 112, rem = job - row * 112;
      const int col = rem >> 2, qt = rem & 3;
      const int rim = h0 - 6 + row, cim = w0 - 6 + col;
      const bool ok = ((unsigned)rim < (unsigned)H_) && ((unsigned)cim < (unsigned)W_);
      ptr[j] = bn + (((size_t)bb * 8 * H_ + (ok ? rim : 0)) * W_ + (ok ? cim : 0)) * 32 + qt * 8;
      if (ok) flags |= 1u << j;
    } else {           // a-tile: 64 px (r*16+m) x 4 quarters
      const int aj = job - 1792;
      const int px = aj >> 2, qt = aj & 3;
      const int r = px >> 4, m = px & 15;
      ptr[j] = an + (((size_t)bb * 8 * H_ + h0 + r) * W_ + w0 + m) * 32 + qt * 8;
      flags |= 1u << j;
    }
  }

  const uint4 z4 = make_uint4(0u, 0u, 0u, 0u);
  #pragma unroll
  for (int j = 0; j < 4; ++j) {
    *(uint4*)((char*)u.stage[0] + (j * 512 + t) * 16) = z4;
    *(uint4*)((char*)u.stage[1] + (j * 512 + t) * 16) = z4;
  }
  __syncthreads();

  #pragma unroll
  for (int j = 0; j < 4; ++j) {
    if (flags & (1u << j))
      gload16(ptr[j], (char*)u.stage[0] + (j * 512 + wv * 64) * 16);
    ptr[j] += KGS;
  }

  floatx4 acc[4][4] = {};  // [uu: jj=jjg+4uu][r]; 13 of 16 valid per wave

  for (int kg = 0; kg < 8; ++kg) {
    __syncthreads();  // drains kg's DMA; all kg-1 frag reads already complete
    if (kg < 7) {
      char* nb = (char*)u.stage[(kg + 1) & 1];
      #pragma unroll
      for (int j = 0; j < 4; ++j) {
        if (flags & (1u << j))
          gload16(ptr[j], nb + (j * 512 + wv * 64) * 16);
        ptr[j] += KGS;
      }
    }
    const _Float16* sb = u.stage[kg & 1];

    half8 A[4];
    #pragma unroll
    for (int r = 0; r < 4; ++r)
      A[r] = *(const half8*)(sb + 14336 + (r * 16 + ml) * 32 + q * 8);

    #pragma unroll
    for (int uu = 0; uu < 4; ++uu) {
      const int jj = jjg + 4 * uu;
      const half8 Bf = *(const half8*)(sb + jj * 896 + (ntile * 16 + ml) * 32 + q * 8);
      #pragma unroll
      for (int r = 0; r < 4; ++r) {
        if ((uu == 0 && r > jjg) || (uu == 3 && r < jjg)) continue;  // dy out of band
        acc[uu][r] = __builtin_amdgcn_mfma_f32_16x16x32_f16(A[r], Bf, acc[uu][r], 0, 0, 0);
      }
    }
  }

  // ---- epilogue: 2 rounds of 2 rows; ostage (22984 B) overlays buf0 only ----
  #pragma unroll
  for (int r2 = 0; r2 < 2; ++r2) {
    if (r2) __syncthreads();
    #pragma unroll
    for (int uu = 0; uu < 4; ++uu) {
      const int jj = jjg + 4 * uu;
      const int col = ntile * 16 + ml;
      #pragma unroll
      for (int rr = 2 * r2; rr < 2 * r2 + 2; ++rr) {
        if ((uu == 0 && rr > jjg) || (uu == 3 && rr < jjg)) continue;
        const int dy6 = jj - rr;  // in [0,12]
        #pragma unroll
        for (int p = 0; p < 4; ++p) {
          const int ip = q * 4 + p;
          const int dx6 = col - ip;
          if (dx6 >= 0 && dx6 <= 12)
            u.ostage[((dy6 * 13 + dx6) * 2 + (rr & 1)) * 17 + ip] = acc[uu][rr][p];
        }
      }
    }
    __syncthreads();
    for (int s = t; s < K2_ * 32; s += 512) {
      const int k = s >> 5, r1 = (s >> 4) & 1, ip = s & 15;
      out[(((size_t)bb * K2_ + k) * H_ + h0 + 2 * r2 + r1) * W_ + w0 + ip] =
          u.ostage[(k * 2 + r1) * 17 + ip];
    }
  }
}

extern "C" void kernel_launch(void* const* d_in, const int* in_sizes, int n_in,
                              void* d_out, int out_size, void* d_ws, size_t ws_size,
                              hipStream_t stream) {
  const float* fa = (const float*)d_in[0];
  const float* fb = (const float*)d_in[1];
  float* out = (float*)d_out;
  _Float16* an = (_Float16*)d_ws;                 // 33.55 MB, [b][kg][h][w][32]
  _Float16* bn = an + (size_t)B_ * H_ * W_ * C_;  // 33.55 MB
  nt_kernel<<<2048, 256, 0, stream>>>(fa, fb, an, bn);
  corr_kernel<<<1024, 512, 0, stream>>>(an, bn, out);
}